// Round 11
// baseline (81.082 us; speedup 1.0000x reference)
//
#include <hip/hip_runtime.h>

#define GS 64
#define BB 128
#define NN 8192
#define KK 3
#define SLICE_FLOATS (GS * GS * GS * 3)   // 786432 floats = 3 MB per b
#define B_PER_XCD 16
#define BLOCKS_PER_B 96                   // 3 k-streams x 32 chunks of 256 pts
#define GRID (BB * BLOCKS_PER_B)          // 12288
#define LDS_PAD 49152                     // 48 KB dynamic LDS -> 3 blocks/CU cap

// One thread = one (b, k, point): reflect+rotate => 2 gathers.
// Occupancy deliberately capped at 3 blocks/CU via 48 KB dynamic LDS:
// 3 blocks/CU x 32 CU = 96 resident blocks per XCD = EXACTLY one b
// (BLOCKS_PER_B = 96) => the live cp slice (3 MB) fits the XCD's 4 MB L2,
// turning every gather from an L3 hit (~350+ cy) into an L2 hit (~220 cy).
// MSHR-limited model: time ~ lines_per_CU * L / M, so latency is the lever.
// No device-scope fences/atomics in the hot path (rounds 4/7/9 lessons).
__global__ __launch_bounds__(256) void symloss_main(
    const float* __restrict__ points, const float* __restrict__ cp,
    const float* __restrict__ plane, const float* __restrict__ quat,
    float2* __restrict__ partials) {
    extern __shared__ char lds_pad[];     // unused; forces 48 KB/block

    int raw = blockIdx.x;
    int xcd = raw & 7;
    int s   = raw >> 3;                   // 0..1535 per XCD
    int b   = xcd * B_PER_XCD + s / BLOCKS_PER_B;
    int j   = s % BLOCKS_PER_B;           // 0..95
    int k   = j % 3;                      // interleave k-streams in time
    int chunk = j / 3;                    // 0..31
    int n = chunk * 256 + threadIdx.x;

    const float* p = points + ((size_t)b * NN + n) * 3;
    float px = p[0], py = p[1], pz = p[2];
    const float* cpb = cp + (size_t)b * SLICE_FLOATS;

    // ---- reflect (b,k uniform per block -> scalar plane/quat loads) ----
    const float* plk = plane + ((size_t)k * BB + b) * 4;
    float nx = plk[0], ny = plk[1], nz = plk[2], d = plk[3];
    float denom = nx * nx + ny * ny + nz * nz + 1e-12f;
    float tt = (px * nx + py * ny + pz * nz + d) / denom;
    float rx = px - 2.0f * tt * nx;
    float ry = py - 2.0f * tt * ny;
    float rz = pz - 2.0f * tt * nz;

    // ---- rotate ----
    const float* q = quat + ((size_t)k * BB + b) * 4;
    float qw = q[0], qx = q[1], qy = q[2], qz = q[3];
    float qn = sqrtf(qw * qw + qx * qx + qy * qy + qz * qz) + 1e-12f;
    qw /= qn; qx /= qn; qy /= qn; qz /= qn;
    float ux = qy * pz - qz * py;
    float uy = qz * px - qx * pz;
    float uz = qx * py - qy * px;
    float sx = ux + qw * px;
    float sy = uy + qw * py;
    float sz = uz + qw * pz;
    float ox = px + 2.0f * (qy * sz - qz * sy);
    float oy = py + 2.0f * (qz * sx - qx * sz);
    float oz = pz + 2.0f * (qx * sy - qy * sx);

    // ---- both flat indices, then both gathers in flight ----
    float fx = fminf(fmaxf(floorf((rx + 0.5f) * 64.0f), 0.0f), 63.0f);
    float fy = fminf(fmaxf(floorf((ry + 0.5f) * 64.0f), 0.0f), 63.0f);
    float fz = fminf(fmaxf(floorf((rz + 0.5f) * 64.0f), 0.0f), 63.0f);
    int flat_r = (((int)fx * GS) + (int)fy) * GS + (int)fz;
    float gx = fminf(fmaxf(floorf((ox + 0.5f) * 64.0f), 0.0f), 63.0f);
    float gy = fminf(fmaxf(floorf((oy + 0.5f) * 64.0f), 0.0f), 63.0f);
    float gz = fminf(fmaxf(floorf((oz + 0.5f) * 64.0f), 0.0f), 63.0f);
    int flat_o = (((int)gx * GS) + (int)gy) * GS + (int)gz;

    const float* cr = cpb + (size_t)flat_r * 3;
    const float* co = cpb + (size_t)flat_o * 3;
    float c0 = cr[0], c1 = cr[1], c2 = cr[2];
    float e0 = co[0], e1 = co[1], e2 = co[2];

    float drx = rx - c0, dry = ry - c1, drz = rz - c2;
    float dox = ox - e0, doy = oy - e1, doz = oz - e2;
    float ref_acc = drx * drx + dry * dry + drz * drz;
    float rot_acc = dox * dox + doy * doy + doz * doz;

    // ---- block reduction: shuffle (width 64) -> LDS -> one plain store ----
    for (int off = 32; off > 0; off >>= 1) {
        ref_acc += __shfl_down(ref_acc, off, 64);
        rot_acc += __shfl_down(rot_acc, off, 64);
    }
    __shared__ float s_ref[4], s_rot[4];
    int wave = threadIdx.x >> 6;
    int lane = threadIdx.x & 63;
    if (lane == 0) {
        s_ref[wave] = ref_acc;
        s_rot[wave] = rot_acc;
    }
    __syncthreads();
    if (threadIdx.x == 0) {
        float2 v;
        v.x = s_ref[0] + s_ref[1] + s_ref[2] + s_ref[3];
        v.y = s_rot[0] + s_rot[1] + s_rot[2] + s_rot[3];
        partials[blockIdx.x] = v;   // distinct slot per block, no atomics
    }
}

// Lean finalize: 256 threads, float4 loads (2 partials each), double accum,
// wave shuffle reduce -> 4 LDS slots -> serial sum.
__global__ __launch_bounds__(256) void finalize_kernel(
    const float4* __restrict__ partials4, float* __restrict__ out) {
    double r = 0.0, o = 0.0;
    for (int i = threadIdx.x; i < GRID / 2; i += 256) {
        float4 v = partials4[i];
        r += (double)v.x + (double)v.z;
        o += (double)v.y + (double)v.w;
    }
    for (int off = 32; off > 0; off >>= 1) {
        r += __shfl_down(r, off, 64);
        o += __shfl_down(o, off, 64);
    }
    __shared__ double s_r[4], s_o[4];
    int wave = threadIdx.x >> 6;
    int lane = threadIdx.x & 63;
    if (lane == 0) {
        s_r[wave] = r;
        s_o[wave] = o;
    }
    __syncthreads();
    if (threadIdx.x == 0) {
        const double inv = 1.0 / ((double)BB * (double)NN);
        out[0] = (float)((s_r[0] + s_r[1] + s_r[2] + s_r[3]) * inv);
        out[1] = (float)((s_o[0] + s_o[1] + s_o[2] + s_o[3]) * inv);
    }
}

extern "C" void kernel_launch(void* const* d_in, const int* in_sizes, int n_in,
                              void* d_out, int out_size, void* d_ws, size_t ws_size,
                              hipStream_t stream) {
    const float* points = (const float*)d_in[0];
    const float* cp     = (const float*)d_in[1];
    // d_in[2] = voxel (unused)
    const float* plane  = (const float*)d_in[3];
    const float* quat   = (const float*)d_in[4];
    float* out = (float*)d_out;
    float2* partials = (float2*)d_ws;     // 12288 * 8 B = 96 KB

    symloss_main<<<GRID, 256, LDS_PAD, stream>>>(points, cp, plane, quat,
                                                 partials);
    finalize_kernel<<<1, 256, 0, stream>>>((const float4*)partials, out);
}